// Round 4
// baseline (888.438 us; speedup 1.0000x reference)
//
#include <hip/hip_runtime.h>
#include <hip/hip_bf16.h>

#define T_TOK 4096
#define HDIM  2048
#define NEXP  64
#define IDIM  768
#define TOPK  4
#define CAPE  512
#define NFLAT (T_TOK*TOPK)

typedef __bf16        bf16x8 __attribute__((ext_vector_type(8)));
typedef float         f32x4  __attribute__((ext_vector_type(4)));
typedef unsigned int  u32x4  __attribute__((ext_vector_type(4)));

// native-cast based conversions (compiler emits v_cvt_pk_bf16_f32-class ops)
__device__ __forceinline__ unsigned short f2bf(float f) {
  __bf16 b = (__bf16)f;
  return __builtin_bit_cast(unsigned short, b);
}
__device__ __forceinline__ unsigned pack2(float lo, float hi) {
  return (unsigned)f2bf(lo) | ((unsigned)f2bf(hi) << 16);
}
// LDS address: row stripe of 128B, 16B chunk xor-swizzled so both staging writes
// (kg-partitioned) and fragment reads (row-partitioned) are conflict-minimal.
__device__ __forceinline__ int swz(int row, int chunk) {
  return row*128 + (((chunk ^ (row & 7) ^ ((row >> 3) & 7)) & 7) << 4);
}

// ---------------- gating: logits, top-4, renorm weights; also hs -> bf16 ----------------
__global__ __launch_bounds__(256) void k_gating(
    const float* __restrict__ hs, const float* __restrict__ gw,
    unsigned short* __restrict__ hs_bf, int* __restrict__ tidx, float* __restrict__ tw)
{
  __shared__ float lg[16][64];
  const int tid = threadIdx.x;
  const int t0  = blockIdx.x * 16;

  {
    const f32x4* src = (const f32x4*)(hs + (size_t)t0 * HDIM);
    for (int i = tid; i < 16 * HDIM / 4; i += 256) {
      f32x4 v = src[i];
      ushort4 o;
      o.x = f2bf(v[0]); o.y = f2bf(v[1]); o.z = f2bf(v[2]); o.w = f2bf(v[3]);
      *(ushort4*)(hs_bf + (size_t)t0 * HDIM + (size_t)i * 4) = o;
    }
  }

  const int lane = tid & 63, wv = tid >> 6;
  {
    const f32x4* gr = (const f32x4*)(gw + (size_t)lane * HDIM);
    const f32x4* x0 = (const f32x4*)(hs + (size_t)(t0 + wv*4 + 0) * HDIM);
    const f32x4* x1 = (const f32x4*)(hs + (size_t)(t0 + wv*4 + 1) * HDIM);
    const f32x4* x2 = (const f32x4*)(hs + (size_t)(t0 + wv*4 + 2) * HDIM);
    const f32x4* x3 = (const f32x4*)(hs + (size_t)(t0 + wv*4 + 3) * HDIM);
    float a0=0.f, a1=0.f, a2=0.f, a3=0.f;
    for (int h = 0; h < HDIM/4; ++h) {
      f32x4 g = gr[h];
      f32x4 v0 = x0[h], v1 = x1[h], v2 = x2[h], v3 = x3[h];
      a0 += g[0]*v0[0] + g[1]*v0[1] + g[2]*v0[2] + g[3]*v0[3];
      a1 += g[0]*v1[0] + g[1]*v1[1] + g[2]*v1[2] + g[3]*v1[3];
      a2 += g[0]*v2[0] + g[1]*v2[1] + g[2]*v2[2] + g[3]*v2[3];
      a3 += g[0]*v3[0] + g[1]*v3[1] + g[2]*v3[2] + g[3]*v3[3];
    }
    lg[wv*4+0][lane] = a0;
    lg[wv*4+1][lane] = a1;
    lg[wv*4+2][lane] = a2;
    lg[wv*4+3][lane] = a3;
  }
  __syncthreads();

  if (tid < 16) {
    const int t = t0 + tid;
    unsigned long long chosen = 0ull;
    float bv[4]; int bi[4];
#pragma unroll
    for (int k = 0; k < 4; ++k) {
      float best = -1e30f; int b = 0;
      for (int e = 0; e < 64; ++e) {
        float v = lg[tid][e];
        if (!((chosen >> e) & 1ull) && v > best) { best = v; b = e; }
      }
      chosen |= 1ull << b; bv[k] = best; bi[k] = b;
    }
    float s = 0.f, w[4];
#pragma unroll
    for (int k = 0; k < 4; ++k) { w[k] = __expf(bv[k] - bv[0]); s += w[k]; }
    float inv = 1.f / s;
#pragma unroll
    for (int k = 0; k < 4; ++k) { tidx[t*4+k] = bi[k]; tw[t*4+k] = w[k] * inv; }
  }
}

// ---------------- per-expert stable rank (ballot scan) ----------------
__global__ __launch_bounds__(64) void k_count_rank(
    const int* __restrict__ tidx, int* __restrict__ rankb, int* __restrict__ counts)
{
  const int e = blockIdx.x;
  const int lane = threadIdx.x;
  int base = 0;
  for (int c = 0; c < NFLAT/64; ++c) {
    int n = c*64 + lane;
    bool m = (tidx[n] == e);
    unsigned long long mask = __ballot(m);
    if (m) rankb[n] = base + __popcll(mask & ((1ull << lane) - 1ull));
    base += __popcll(mask);
  }
  if (lane == 0) counts[e] = base;
}

// ---------------- starts scan + sorted-row maps ----------------
__global__ __launch_bounds__(256) void k_build(
    const int* __restrict__ tidx, const int* __restrict__ rankb,
    const int* __restrict__ counts,
    int* __restrict__ starts, int* __restrict__ row_info, int* __restrict__ sortpos)
{
  __shared__ int s_starts[NEXP];
  if (threadIdx.x == 0) {
    int s = 0;
    for (int e = 0; e < NEXP; ++e) { s_starts[e] = s; starts[e] = s; s += counts[e]; }
  }
  __syncthreads();
  for (int n = threadIdx.x; n < NFLAT; n += 256) {
    int e = tidx[n], r = rankb[n];
    int sr = s_starts[e] + r;
    row_info[sr] = n;
    sortpos[n] = (r < CAPE) ? sr : -1;
  }
}

// ---------------- GEMM1 (gather A) + fused SwiGLU -> a_buf (bf16) ----------------
// grid (nt, e); internal m-loop (256 rows/iter); double-buffered LDS, 1 barrier/K-step.
__global__ __launch_bounds__(512, 2) void k_gemm1(
    const unsigned short* __restrict__ hs_bf, const float* __restrict__ w13,
    const int* __restrict__ counts, const int* __restrict__ starts,
    const int* __restrict__ row_info, unsigned short* __restrict__ a_buf)
{
  const int nt = blockIdx.x;   // 0..5   (128 i-cols, both halves)
  const int e  = blockIdx.y;   // 0..63
  const int count = min(counts[e], CAPE);
  if (count <= 0) return;
  const int nmt = (count + 255) >> 8;
  const int tid = threadIdx.x;
  const int estart = starts[e];

  // per buffer: A [256][128B] @0 (32KB), Bg [128][128B] @32768, Bu @49152 -> 64KB; x2 buffers
  __shared__ __align__(16) char lds[2*65536];

  const int mrow = tid >> 3, cchunk = tid & 7;
  const float* w13e = w13 + (size_t)e * HDIM * (2*IDIM);
  const int half = tid >> 8;        // 0=gate half, 1=up half
  const int t8   = tid & 255;
  const int kg   = t8 >> 5;         // k-group of 8
  const int n4   = (t8 & 31) * 4;
  const int lane = tid & 63, wv = tid >> 6;
  const int wr = wv >> 1, wc = wv & 1;

  int cur = 0;
  for (int mi = 0; mi < nmt; ++mi) {
    const int R0 = mi << 8;
    const int base_sorted = estart + R0;
    int tokp[4];
#pragma unroll
    for (int p = 0; p < 4; ++p) {
      int sr = base_sorted + mrow + p*64;
      if (sr > NFLAT-1) sr = NFLAT-1;
      tokp[p] = row_info[sr] >> 2;
    }
    f32x4 accg[4][4], accu[4][4];
#pragma unroll
    for (int i = 0; i < 4; ++i)
#pragma unroll
      for (int j = 0; j < 4; ++j) { accg[i][j] = f32x4{0.f,0.f,0.f,0.f}; accu[i][j] = f32x4{0.f,0.f,0.f,0.f}; }

    u32x4 rA[4]; f32x4 rB[8];
    // prologue: load k-tile 0
#pragma unroll
    for (int p = 0; p < 4; ++p)
      rA[p] = *(const u32x4*)(hs_bf + (size_t)tokp[p]*HDIM + cchunk*8);
    {
      const float* bp = w13e + (size_t)(kg*8) * (2*IDIM) + half*IDIM + nt*128 + n4;
#pragma unroll
      for (int j = 0; j < 8; ++j) rB[j] = *(const f32x4*)(bp + (size_t)j * (2*IDIM));
    }
    __syncthreads();   // protect buf[cur] from previous m-iter readers
    {
      char* A0 = lds + cur*65536;
      char* B0 = lds + cur*65536 + 32768 + half*16384;
#pragma unroll
      for (int p = 0; p < 4; ++p)
        *(u32x4*)(A0 + swz(mrow + p*64, cchunk)) = rA[p];
#pragma unroll
      for (int i = 0; i < 4; ++i) {
        u32x4 q;
        q[0] = pack2(rB[0][i], rB[1][i]);
        q[1] = pack2(rB[2][i], rB[3][i]);
        q[2] = pack2(rB[4][i], rB[5][i]);
        q[3] = pack2(rB[6][i], rB[7][i]);
        *(u32x4*)(B0 + swz(n4 + i, kg)) = q;
      }
    }

    for (int kt = 0; kt < HDIM/64; ++kt) {
      __syncthreads();   // buf[cur] writes visible; prior readers of buf[cur^1] done
      const bool pf = (kt+1 < HDIM/64);
      if (pf) {
#pragma unroll
        for (int p = 0; p < 4; ++p)
          rA[p] = *(const u32x4*)(hs_bf + (size_t)tokp[p]*HDIM + (kt+1)*64 + cchunk*8);
        const float* bp = w13e + (size_t)((kt+1)*64 + kg*8) * (2*IDIM) + half*IDIM + nt*128 + n4;
#pragma unroll
        for (int j = 0; j < 8; ++j) rB[j] = *(const f32x4*)(bp + (size_t)j * (2*IDIM));
      }
      char* Ac  = lds + cur*65536;
      char* Bgc = lds + cur*65536 + 32768;
      char* Buc = Bgc + 16384;
#pragma unroll
      for (int kfi = 0; kfi < 2; ++kfi) {
        const int ch = (kfi<<2) | (lane>>4);
        bf16x8 af[4], bg[4], bu[4];
#pragma unroll
        for (int mi2 = 0; mi2 < 4; ++mi2) {
          int row = wr*64 + mi2*16 + (lane & 15);
          af[mi2] = *(const bf16x8*)(Ac + swz(row, ch));
        }
#pragma unroll
        for (int ni = 0; ni < 4; ++ni) {
          int n = wc*64 + ni*16 + (lane & 15);
          bg[ni] = *(const bf16x8*)(Bgc + swz(n, ch));
          bu[ni] = *(const bf16x8*)(Buc + swz(n, ch));
        }
#pragma unroll
        for (int mi2 = 0; mi2 < 4; ++mi2)
#pragma unroll
          for (int ni = 0; ni < 4; ++ni) {
            accg[mi2][ni] = __builtin_amdgcn_mfma_f32_16x16x32_bf16(af[mi2], bg[ni], accg[mi2][ni], 0, 0, 0);
            accu[mi2][ni] = __builtin_amdgcn_mfma_f32_16x16x32_bf16(af[mi2], bu[ni], accu[mi2][ni], 0, 0, 0);
          }
      }
      if (pf) {
        char* An = lds + (cur^1)*65536;
        char* Bn = lds + (cur^1)*65536 + 32768 + half*16384;
#pragma unroll
        for (int p = 0; p < 4; ++p)
          *(u32x4*)(An + swz(mrow + p*64, cchunk)) = rA[p];
#pragma unroll
        for (int i = 0; i < 4; ++i) {
          u32x4 q;
          q[0] = pack2(rB[0][i], rB[1][i]);
          q[1] = pack2(rB[2][i], rB[3][i]);
          q[2] = pack2(rB[4][i], rB[5][i]);
          q[3] = pack2(rB[6][i], rB[7][i]);
          *(u32x4*)(Bn + swz(n4 + i, kg)) = q;
        }
      }
      cur ^= 1;
    }

    // epilogue: silu(g)*u -> a_buf (bf16)
#pragma unroll
    for (int mi2 = 0; mi2 < 4; ++mi2) {
#pragma unroll
      for (int j = 0; j < 4; ++j) {
        int rl = wr*64 + mi2*16 + (lane >> 4)*4 + j;
        if (R0 + rl < count) {
          size_t rowoff = (size_t)(base_sorted + rl) * IDIM;
#pragma unroll
          for (int ni = 0; ni < 4; ++ni) {
            int col = nt*128 + wc*64 + ni*16 + (lane & 15);
            float g = accg[mi2][ni][j], u = accu[mi2][ni][j];
            float a = (g / (1.f + __expf(-g))) * u;
            a_buf[rowoff + col] = f2bf(a);
          }
        }
      }
    }
  }
}

// ---------------- GEMM2 -> y_buf (bf16, sorted rows, unweighted) ----------------
// grid (nt, e); internal m-loop; double-buffered LDS, 1 barrier/K-step.
__global__ __launch_bounds__(512, 2) void k_gemm2(
    const unsigned short* __restrict__ a_buf, const float* __restrict__ w2,
    const int* __restrict__ counts, const int* __restrict__ starts,
    unsigned short* __restrict__ y_buf)
{
  const int nt = blockIdx.x;   // 0..7  (256 cols each)
  const int e  = blockIdx.y;   // 0..63
  const int count = min(counts[e], CAPE);
  if (count <= 0) return;
  const int nmt = (count + 255) >> 8;
  const int tid = threadIdx.x;
  const int estart = starts[e];

  // per buffer: A [256][128B] @0 (32KB), B [256][128B] @32768 (32KB); x2
  __shared__ __align__(16) char lds[2*65536];

  const int mrow = tid >> 3, cchunk = tid & 7;
  const float* w2e = w2 + (size_t)e * IDIM * HDIM;
  const int pass = tid >> 8;        // which 128-col group this thread stages
  const int t8   = tid & 255;
  const int kg   = t8 >> 5, n4 = (t8 & 31) * 4;
  const int lane = tid & 63, wv = tid >> 6, wr = wv >> 1, wc = wv & 1;

  int cur = 0;
  for (int mi = 0; mi < nmt; ++mi) {
    const int R0 = mi << 8;
    const int base_sorted = estart + R0;
    int srp[4];
#pragma unroll
    for (int p = 0; p < 4; ++p) {
      int sr = base_sorted + mrow + p*64;
      srp[p] = (sr > NFLAT-1) ? (NFLAT-1) : sr;
    }
    f32x4 acc[4][8];
#pragma unroll
    for (int i = 0; i < 4; ++i)
#pragma unroll
      for (int j = 0; j < 8; ++j) acc[i][j] = f32x4{0.f,0.f,0.f,0.f};

    u32x4 rA[4]; f32x4 rB[8];
#pragma unroll
    for (int p = 0; p < 4; ++p)
      rA[p] = *(const u32x4*)(a_buf + (size_t)srp[p]*IDIM + cchunk*8);
    {
      const float* bp = w2e + (size_t)(kg*8) * HDIM + nt*256 + pass*128 + n4;
#pragma unroll
      for (int j = 0; j < 8; ++j) rB[j] = *(const f32x4*)(bp + (size_t)j * HDIM);
    }
    __syncthreads();
    {
      char* A0 = lds + cur*65536;
      char* B0 = lds + cur*65536 + 32768;
#pragma unroll
      for (int p = 0; p < 4; ++p)
        *(u32x4*)(A0 + swz(mrow + p*64, cchunk)) = rA[p];
#pragma unroll
      for (int i = 0; i < 4; ++i) {
        int n = pass*128 + n4 + i;
        u32x4 q;
        q[0] = pack2(rB[0][i], rB[1][i]);
        q[1] = pack2(rB[2][i], rB[3][i]);
        q[2] = pack2(rB[4][i], rB[5][i]);
        q[3] = pack2(rB[6][i], rB[7][i]);
        *(u32x4*)(B0 + swz(n, kg)) = q;
      }
    }

    for (int kt = 0; kt < IDIM/64; ++kt) {
      __syncthreads();
      const bool pf = (kt+1 < IDIM/64);
      if (pf) {
#pragma unroll
        for (int p = 0; p < 4; ++p)
          rA[p] = *(const u32x4*)(a_buf + (size_t)srp[p]*IDIM + (kt+1)*64 + cchunk*8);
        const float* bp = w2e + (size_t)((kt+1)*64 + kg*8) * HDIM + nt*256 + pass*128 + n4;
#pragma unroll
        for (int j = 0; j < 8; ++j) rB[j] = *(const f32x4*)(bp + (size_t)j * HDIM);
      }
      char* Ac = lds + cur*65536;
      char* Bc = lds + cur*65536 + 32768;
#pragma unroll
      for (int kfi = 0; kfi < 2; ++kfi) {
        const int ch = (kfi<<2) | (lane>>4);
        bf16x8 af[4], bb[8];
#pragma unroll
        for (int mi2 = 0; mi2 < 4; ++mi2) {
          int row = wr*64 + mi2*16 + (lane & 15);
          af[mi2] = *(const bf16x8*)(Ac + swz(row, ch));
        }
#pragma unroll
        for (int ni = 0; ni < 8; ++ni) {
          int n = wc*128 + ni*16 + (lane & 15);
          bb[ni] = *(const bf16x8*)(Bc + swz(n, ch));
        }
#pragma unroll
        for (int mi2 = 0; mi2 < 4; ++mi2)
#pragma unroll
          for (int ni = 0; ni < 8; ++ni)
            acc[mi2][ni] = __builtin_amdgcn_mfma_f32_16x16x32_bf16(af[mi2], bb[ni], acc[mi2][ni], 0, 0, 0);
      }
      if (pf) {
        char* An = lds + (cur^1)*65536;
        char* Bn = lds + (cur^1)*65536 + 32768;
#pragma unroll
        for (int p = 0; p < 4; ++p)
          *(u32x4*)(An + swz(mrow + p*64, cchunk)) = rA[p];
#pragma unroll
        for (int i = 0; i < 4; ++i) {
          int n = pass*128 + n4 + i;
          u32x4 q;
          q[0] = pack2(rB[0][i], rB[1][i]);
          q[1] = pack2(rB[2][i], rB[3][i]);
          q[2] = pack2(rB[4][i], rB[5][i]);
          q[3] = pack2(rB[6][i], rB[7][i]);
          *(u32x4*)(Bn + swz(n, kg)) = q;
        }
      }
      cur ^= 1;
    }

    // epilogue: bf16 stores of unweighted y rows
#pragma unroll
    for (int mi2 = 0; mi2 < 4; ++mi2) {
#pragma unroll
      for (int j = 0; j < 4; ++j) {
        int rl = wr*64 + mi2*16 + (lane >> 4)*4 + j;
        if (R0 + rl < count) {
          int sr = base_sorted + rl;
          unsigned short* yrow = y_buf + (size_t)sr * HDIM;
#pragma unroll
          for (int ni = 0; ni < 8; ++ni) {
            int col = nt*256 + wc*128 + ni*16 + (lane & 15);
            yrow[col] = f2bf(acc[mi2][ni][j]);
          }
        }
      }
    }
  }
}

// ---------------- finalize: out[t] = sum_k tw[t,k] * y_buf[sortpos[t,k]] ----------------
__global__ __launch_bounds__(256) void k_finalize(
    const unsigned short* __restrict__ y_buf, const int* __restrict__ sortpos,
    const float* __restrict__ tw, float* __restrict__ out)
{
  const int t = blockIdx.x;
  const int tid = threadIdx.x;   // each thread: 8 consecutive cols
  float acc[8];
#pragma unroll
  for (int i = 0; i < 8; ++i) acc[i] = 0.f;
#pragma unroll
  for (int k = 0; k < 4; ++k) {
    int sp = sortpos[t*4+k];
    float w = tw[t*4+k];
    if (sp >= 0) {
      u32x4 v = *(const u32x4*)(y_buf + (size_t)sp * HDIM + tid*8);
#pragma unroll
      for (int q = 0; q < 4; ++q) {
        float lo = __builtin_bit_cast(float, v[q] << 16);
        float hi = __builtin_bit_cast(float, v[q] & 0xffff0000u);
        acc[2*q]   += w * lo;
        acc[2*q+1] += w * hi;
      }
    }
  }
  f32x4 o0 = {acc[0], acc[1], acc[2], acc[3]};
  f32x4 o1 = {acc[4], acc[5], acc[6], acc[7]};
  f32x4* o = (f32x4*)(out + (size_t)t * HDIM + tid*8);
  o[0] = o0;
  o[1] = o1;
}

extern "C" void kernel_launch(void* const* d_in, const int* in_sizes, int n_in,
                              void* d_out, int out_size, void* d_ws, size_t ws_size,
                              hipStream_t stream) {
  const float* hs  = (const float*)d_in[0];
  const float* gw  = (const float*)d_in[1];
  const float* w13 = (const float*)d_in[2];
  const float* w2  = (const float*)d_in[3];
  float* out = (float*)d_out;

  char* ws = (char*)d_ws;
  size_t off = 0;
  auto alloc = [&](size_t bytes) {
    off = (off + 255) & ~(size_t)255;
    char* p = ws + off;
    off += bytes;
    return p;
  };
  unsigned short* hs_bf = (unsigned short*)alloc((size_t)T_TOK * HDIM * 2);
  int*   tidx   = (int*)  alloc((size_t)NFLAT * 4);
  float* tw     = (float*)alloc((size_t)NFLAT * 4);
  int*   rankb  = (int*)  alloc((size_t)NFLAT * 4);
  int*   counts = (int*)  alloc((size_t)NEXP * 4);
  int*   starts = (int*)  alloc((size_t)NEXP * 4);
  int*   rinfo  = (int*)  alloc((size_t)NFLAT * 4);
  int*   sortp  = (int*)  alloc((size_t)NFLAT * 4);
  unsigned short* a_buf = (unsigned short*)alloc((size_t)NFLAT * IDIM * 2);
  unsigned short* y_buf = (unsigned short*)alloc((size_t)NFLAT * HDIM * 2);
  (void)ws_size; (void)in_sizes; (void)n_in; (void)out_size;

  k_gating<<<T_TOK/16, 256, 0, stream>>>(hs, gw, hs_bf, tidx, tw);
  k_count_rank<<<NEXP, 64, 0, stream>>>(tidx, rankb, counts);
  k_build<<<1, 256, 0, stream>>>(tidx, rankb, counts, starts, rinfo, sortp);
  k_gemm1<<<dim3(6, NEXP), 512, 0, stream>>>(hs_bf, w13, counts, starts, rinfo, a_buf);
  k_gemm2<<<dim3(8, NEXP), 512, 0, stream>>>(a_buf, w2, counts, starts, y_buf);
  k_finalize<<<T_TOK, 256, 0, stream>>>(y_buf, sortp, tw, out);
}

// Round 5
// 884.448 us; speedup vs baseline: 1.0045x; 1.0045x over previous
//
#include <hip/hip_runtime.h>
#include <hip/hip_bf16.h>

#define T_TOK 4096
#define HDIM  2048
#define NEXP  64
#define IDIM  768
#define TOPK  4
#define CAPE  512
#define NFLAT (T_TOK*TOPK)

typedef __bf16        bf16x8 __attribute__((ext_vector_type(8)));
typedef float         f32x4  __attribute__((ext_vector_type(4)));
typedef unsigned int  u32x4  __attribute__((ext_vector_type(4)));

// native-cast based conversions (compiler emits v_cvt_pk_bf16_f32-class ops)
__device__ __forceinline__ unsigned short f2bf(float f) {
  __bf16 b = (__bf16)f;
  return __builtin_bit_cast(unsigned short, b);
}
__device__ __forceinline__ unsigned pack2(float lo, float hi) {
  return (unsigned)f2bf(lo) | ((unsigned)f2bf(hi) << 16);
}
// LDS address: row stripe of 128B, 16B chunk xor-swizzled so both staging writes
// (kg-partitioned) and fragment reads (row-partitioned) are conflict-minimal.
__device__ __forceinline__ int swz(int row, int chunk) {
  return row*128 + (((chunk ^ (row & 7) ^ ((row >> 3) & 7)) & 7) << 4);
}

// ---------------- gating: logits, top-4, renorm weights; also hs -> bf16 ----------------
__global__ __launch_bounds__(256) void k_gating(
    const float* __restrict__ hs, const float* __restrict__ gw,
    unsigned short* __restrict__ hs_bf, int* __restrict__ tidx, float* __restrict__ tw)
{
  __shared__ float lg[16][64];
  const int tid = threadIdx.x;
  const int t0  = blockIdx.x * 16;

  {
    const f32x4* src = (const f32x4*)(hs + (size_t)t0 * HDIM);
    for (int i = tid; i < 16 * HDIM / 4; i += 256) {
      f32x4 v = src[i];
      ushort4 o;
      o.x = f2bf(v[0]); o.y = f2bf(v[1]); o.z = f2bf(v[2]); o.w = f2bf(v[3]);
      *(ushort4*)(hs_bf + (size_t)t0 * HDIM + (size_t)i * 4) = o;
    }
  }

  const int lane = tid & 63, wv = tid >> 6;
  {
    const f32x4* gr = (const f32x4*)(gw + (size_t)lane * HDIM);
    const f32x4* x0 = (const f32x4*)(hs + (size_t)(t0 + wv*4 + 0) * HDIM);
    const f32x4* x1 = (const f32x4*)(hs + (size_t)(t0 + wv*4 + 1) * HDIM);
    const f32x4* x2 = (const f32x4*)(hs + (size_t)(t0 + wv*4 + 2) * HDIM);
    const f32x4* x3 = (const f32x4*)(hs + (size_t)(t0 + wv*4 + 3) * HDIM);
    float a0=0.f, a1=0.f, a2=0.f, a3=0.f;
    for (int h = 0; h < HDIM/4; ++h) {
      f32x4 g = gr[h];
      f32x4 v0 = x0[h], v1 = x1[h], v2 = x2[h], v3 = x3[h];
      a0 += g[0]*v0[0] + g[1]*v0[1] + g[2]*v0[2] + g[3]*v0[3];
      a1 += g[0]*v1[0] + g[1]*v1[1] + g[2]*v1[2] + g[3]*v1[3];
      a2 += g[0]*v2[0] + g[1]*v2[1] + g[2]*v2[2] + g[3]*v2[3];
      a3 += g[0]*v3[0] + g[1]*v3[1] + g[2]*v3[2] + g[3]*v3[3];
    }
    lg[wv*4+0][lane] = a0;
    lg[wv*4+1][lane] = a1;
    lg[wv*4+2][lane] = a2;
    lg[wv*4+3][lane] = a3;
  }
  __syncthreads();

  if (tid < 16) {
    const int t = t0 + tid;
    unsigned long long chosen = 0ull;
    float bv[4]; int bi[4];
#pragma unroll
    for (int k = 0; k < 4; ++k) {
      float best = -1e30f; int b = 0;
      for (int e = 0; e < 64; ++e) {
        float v = lg[tid][e];
        if (!((chosen >> e) & 1ull) && v > best) { best = v; b = e; }
      }
      chosen |= 1ull << b; bv[k] = best; bi[k] = b;
    }
    float s = 0.f, w[4];
#pragma unroll
    for (int k = 0; k < 4; ++k) { w[k] = __expf(bv[k] - bv[0]); s += w[k]; }
    float inv = 1.f / s;
#pragma unroll
    for (int k = 0; k < 4; ++k) { tidx[t*4+k] = bi[k]; tw[t*4+k] = w[k] * inv; }
  }
}

// ---------------- per-expert stable rank (ballot scan) ----------------
__global__ __launch_bounds__(64) void k_count_rank(
    const int* __restrict__ tidx, int* __restrict__ rankb, int* __restrict__ counts)
{
  const int e = blockIdx.x;
  const int lane = threadIdx.x;
  int base = 0;
  for (int c = 0; c < NFLAT/64; ++c) {
    int n = c*64 + lane;
    bool m = (tidx[n] == e);
    unsigned long long mask = __ballot(m);
    if (m) rankb[n] = base + __popcll(mask & ((1ull << lane) - 1ull));
    base += __popcll(mask);
  }
  if (lane == 0) counts[e] = base;
}

// ---------------- starts scan + sorted-row maps ----------------
__global__ __launch_bounds__(256) void k_build(
    const int* __restrict__ tidx, const int* __restrict__ rankb,
    const int* __restrict__ counts,
    int* __restrict__ starts, int* __restrict__ row_info, int* __restrict__ sortpos)
{
  __shared__ int s_starts[NEXP];
  if (threadIdx.x == 0) {
    int s = 0;
    for (int e = 0; e < NEXP; ++e) { s_starts[e] = s; starts[e] = s; s += counts[e]; }
  }
  __syncthreads();
  for (int n = threadIdx.x; n < NFLAT; n += 256) {
    int e = tidx[n], r = rankb[n];
    int sr = s_starts[e] + r;
    row_info[sr] = n;
    sortpos[n] = (r < CAPE) ? sr : -1;
  }
}

// ---------------- GEMM1 (gather A) + fused SwiGLU -> a_buf (bf16) ----------------
// grid (nt, e); internal m-loop (256 rows/iter); double-buffered LDS, 1 barrier/K-step.
__global__ __launch_bounds__(512, 2) void k_gemm1(
    const unsigned short* __restrict__ hs_bf, const float* __restrict__ w13,
    const int* __restrict__ counts, const int* __restrict__ starts,
    const int* __restrict__ row_info, unsigned short* __restrict__ a_buf)
{
  const int nt = blockIdx.x;   // 0..5   (128 i-cols, both halves)
  const int e  = blockIdx.y;   // 0..63
  const int count = min(counts[e], CAPE);
  if (count <= 0) return;
  const int nmt = (count + 255) >> 8;
  const int tid = threadIdx.x;
  const int estart = starts[e];

  // per buffer: A [256][128B] @0 (32KB), Bg [128][128B] @32768, Bu @49152 -> 64KB; x2 buffers
  __shared__ __align__(16) char lds[2*65536];

  const int mrow = tid >> 3, cchunk = tid & 7;
  const float* w13e = w13 + (size_t)e * HDIM * (2*IDIM);
  const int half = tid >> 8;        // 0=gate half, 1=up half
  const int t8   = tid & 255;
  const int kg   = t8 >> 5;         // k-group of 8
  const int n4   = (t8 & 31) * 4;
  const int lane = tid & 63, wv = tid >> 6;
  const int wr = wv >> 1, wc = wv & 1;

  int cur = 0;
  for (int mi = 0; mi < nmt; ++mi) {
    const int R0 = mi << 8;
    const int base_sorted = estart + R0;
    int tokp[4];
#pragma unroll
    for (int p = 0; p < 4; ++p) {
      int sr = base_sorted + mrow + p*64;
      if (sr > NFLAT-1) sr = NFLAT-1;
      tokp[p] = row_info[sr] >> 2;
    }
    f32x4 accg[4][4], accu[4][4];
#pragma unroll
    for (int i = 0; i < 4; ++i)
#pragma unroll
      for (int j = 0; j < 4; ++j) { accg[i][j] = f32x4{0.f,0.f,0.f,0.f}; accu[i][j] = f32x4{0.f,0.f,0.f,0.f}; }

    u32x4 rA[4]; f32x4 rB[8];
    // prologue: load k-tile 0
#pragma unroll
    for (int p = 0; p < 4; ++p)
      rA[p] = *(const u32x4*)(hs_bf + (size_t)tokp[p]*HDIM + cchunk*8);
    {
      const float* bp = w13e + (size_t)(kg*8) * (2*IDIM) + half*IDIM + nt*128 + n4;
#pragma unroll
      for (int j = 0; j < 8; ++j) rB[j] = *(const f32x4*)(bp + (size_t)j * (2*IDIM));
    }
    __syncthreads();   // protect buf[cur] from previous m-iter readers
    {
      char* A0 = lds + cur*65536;
      char* B0 = lds + cur*65536 + 32768 + half*16384;
#pragma unroll
      for (int p = 0; p < 4; ++p)
        *(u32x4*)(A0 + swz(mrow + p*64, cchunk)) = rA[p];
#pragma unroll
      for (int i = 0; i < 4; ++i) {
        u32x4 q;
        q[0] = pack2(rB[0][i], rB[1][i]);
        q[1] = pack2(rB[2][i], rB[3][i]);
        q[2] = pack2(rB[4][i], rB[5][i]);
        q[3] = pack2(rB[6][i], rB[7][i]);
        *(u32x4*)(B0 + swz(n4 + i, kg)) = q;
      }
    }

    for (int kt = 0; kt < HDIM/64; ++kt) {
      __syncthreads();   // buf[cur] writes visible; prior readers of buf[cur^1] done
      const bool pf = (kt+1 < HDIM/64);
      if (pf) {
#pragma unroll
        for (int p = 0; p < 4; ++p)
          rA[p] = *(const u32x4*)(hs_bf + (size_t)tokp[p]*HDIM + (kt+1)*64 + cchunk*8);
        const float* bp = w13e + (size_t)((kt+1)*64 + kg*8) * (2*IDIM) + half*IDIM + nt*128 + n4;
#pragma unroll
        for (int j = 0; j < 8; ++j) rB[j] = *(const f32x4*)(bp + (size_t)j * (2*IDIM));
      }
      char* Ac  = lds + cur*65536;
      char* Bgc = lds + cur*65536 + 32768;
      char* Buc = Bgc + 16384;
#pragma unroll
      for (int kfi = 0; kfi < 2; ++kfi) {
        const int ch = (kfi<<2) | (lane>>4);
        bf16x8 af[4], bg[4], bu[4];
#pragma unroll
        for (int mi2 = 0; mi2 < 4; ++mi2) {
          int row = wr*64 + mi2*16 + (lane & 15);
          af[mi2] = *(const bf16x8*)(Ac + swz(row, ch));
        }
#pragma unroll
        for (int ni = 0; ni < 4; ++ni) {
          int n = wc*64 + ni*16 + (lane & 15);
          bg[ni] = *(const bf16x8*)(Bgc + swz(n, ch));
          bu[ni] = *(const bf16x8*)(Buc + swz(n, ch));
        }
#pragma unroll
        for (int mi2 = 0; mi2 < 4; ++mi2)
#pragma unroll
          for (int ni = 0; ni < 4; ++ni) {
            accg[mi2][ni] = __builtin_amdgcn_mfma_f32_16x16x32_bf16(af[mi2], bg[ni], accg[mi2][ni], 0, 0, 0);
            accu[mi2][ni] = __builtin_amdgcn_mfma_f32_16x16x32_bf16(af[mi2], bu[ni], accu[mi2][ni], 0, 0, 0);
          }
      }
      if (pf) {
        char* An = lds + (cur^1)*65536;
        char* Bn = lds + (cur^1)*65536 + 32768 + half*16384;
#pragma unroll
        for (int p = 0; p < 4; ++p)
          *(u32x4*)(An + swz(mrow + p*64, cchunk)) = rA[p];
#pragma unroll
        for (int i = 0; i < 4; ++i) {
          u32x4 q;
          q[0] = pack2(rB[0][i], rB[1][i]);
          q[1] = pack2(rB[2][i], rB[3][i]);
          q[2] = pack2(rB[4][i], rB[5][i]);
          q[3] = pack2(rB[6][i], rB[7][i]);
          *(u32x4*)(Bn + swz(n4 + i, kg)) = q;
        }
      }
      cur ^= 1;
    }

    // epilogue: silu(g)*u -> a_buf (bf16)
#pragma unroll
    for (int mi2 = 0; mi2 < 4; ++mi2) {
#pragma unroll
      for (int j = 0; j < 4; ++j) {
        int rl = wr*64 + mi2*16 + (lane >> 4)*4 + j;
        if (R0 + rl < count) {
          size_t rowoff = (size_t)(base_sorted + rl) * IDIM;
#pragma unroll
          for (int ni = 0; ni < 4; ++ni) {
            int col = nt*128 + wc*64 + ni*16 + (lane & 15);
            float g = accg[mi2][ni][j], u = accu[mi2][ni][j];
            float a = (g / (1.f + __expf(-g))) * u;
            a_buf[rowoff + col] = f2bf(a);
          }
        }
      }
    }
  }
}

// ---------------- GEMM2 -> y_buf (bf16, sorted rows, unweighted) ----------------
// grid (nt, e); internal m-loop; double-buffered LDS, 1 barrier/K-step.
__global__ __launch_bounds__(512, 2) void k_gemm2(
    const unsigned short* __restrict__ a_buf, const float* __restrict__ w2,
    const int* __restrict__ counts, const int* __restrict__ starts,
    unsigned short* __restrict__ y_buf)
{
  const int nt = blockIdx.x;   // 0..7  (256 cols each)
  const int e  = blockIdx.y;   // 0..63
  const int count = min(counts[e], CAPE);
  if (count <= 0) return;
  const int nmt = (count + 255) >> 8;
  const int tid = threadIdx.x;
  const int estart = starts[e];

  // per buffer: A [256][128B] @0 (32KB), B [256][128B] @32768 (32KB); x2
  __shared__ __align__(16) char lds[2*65536];

  const int mrow = tid >> 3, cchunk = tid & 7;
  const float* w2e = w2 + (size_t)e * IDIM * HDIM;
  const int pass = tid >> 8;        // which 128-col group this thread stages
  const int t8   = tid & 255;
  const int kg   = t8 >> 5, n4 = (t8 & 31) * 4;
  const int lane = tid & 63, wv = tid >> 6, wr = wv >> 1, wc = wv & 1;

  int cur = 0;
  for (int mi = 0; mi < nmt; ++mi) {
    const int R0 = mi << 8;
    const int base_sorted = estart + R0;
    int srp[4];
#pragma unroll
    for (int p = 0; p < 4; ++p) {
      int sr = base_sorted + mrow + p*64;
      srp[p] = (sr > NFLAT-1) ? (NFLAT-1) : sr;
    }
    f32x4 acc[4][8];
#pragma unroll
    for (int i = 0; i < 4; ++i)
#pragma unroll
      for (int j = 0; j < 8; ++j) acc[i][j] = f32x4{0.f,0.f,0.f,0.f};

    u32x4 rA[4]; f32x4 rB[8];
#pragma unroll
    for (int p = 0; p < 4; ++p)
      rA[p] = *(const u32x4*)(a_buf + (size_t)srp[p]*IDIM + cchunk*8);
    {
      const float* bp = w2e + (size_t)(kg*8) * HDIM + nt*256 + pass*128 + n4;
#pragma unroll
      for (int j = 0; j < 8; ++j) rB[j] = *(const f32x4*)(bp + (size_t)j * HDIM);
    }
    __syncthreads();
    {
      char* A0 = lds + cur*65536;
      char* B0 = lds + cur*65536 + 32768;
#pragma unroll
      for (int p = 0; p < 4; ++p)
        *(u32x4*)(A0 + swz(mrow + p*64, cchunk)) = rA[p];
#pragma unroll
      for (int i = 0; i < 4; ++i) {
        int n = pass*128 + n4 + i;
        u32x4 q;
        q[0] = pack2(rB[0][i], rB[1][i]);
        q[1] = pack2(rB[2][i], rB[3][i]);
        q[2] = pack2(rB[4][i], rB[5][i]);
        q[3] = pack2(rB[6][i], rB[7][i]);
        *(u32x4*)(B0 + swz(n, kg)) = q;
      }
    }

    for (int kt = 0; kt < IDIM/64; ++kt) {
      __syncthreads();
      const bool pf = (kt+1 < IDIM/64);
      if (pf) {
#pragma unroll
        for (int p = 0; p < 4; ++p)
          rA[p] = *(const u32x4*)(a_buf + (size_t)srp[p]*IDIM + (kt+1)*64 + cchunk*8);
        const float* bp = w2e + (size_t)((kt+1)*64 + kg*8) * HDIM + nt*256 + pass*128 + n4;
#pragma unroll
        for (int j = 0; j < 8; ++j) rB[j] = *(const f32x4*)(bp + (size_t)j * HDIM);
      }
      char* Ac = lds + cur*65536;
      char* Bc = lds + cur*65536 + 32768;
#pragma unroll
      for (int kfi = 0; kfi < 2; ++kfi) {
        const int ch = (kfi<<2) | (lane>>4);
        bf16x8 af[4], bb[8];
#pragma unroll
        for (int mi2 = 0; mi2 < 4; ++mi2) {
          int row = wr*64 + mi2*16 + (lane & 15);
          af[mi2] = *(const bf16x8*)(Ac + swz(row, ch));
        }
#pragma unroll
        for (int ni = 0; ni < 8; ++ni) {
          int n = wc*128 + ni*16 + (lane & 15);
          bb[ni] = *(const bf16x8*)(Bc + swz(n, ch));
        }
#pragma unroll
        for (int mi2 = 0; mi2 < 4; ++mi2)
#pragma unroll
          for (int ni = 0; ni < 8; ++ni)
            acc[mi2][ni] = __builtin_amdgcn_mfma_f32_16x16x32_bf16(af[mi2], bb[ni], acc[mi2][ni], 0, 0, 0);
      }
      if (pf) {
        char* An = lds + (cur^1)*65536;
        char* Bn = lds + (cur^1)*65536 + 32768;
#pragma unroll
        for (int p = 0; p < 4; ++p)
          *(u32x4*)(An + swz(mrow + p*64, cchunk)) = rA[p];
#pragma unroll
        for (int i = 0; i < 4; ++i) {
          int n = pass*128 + n4 + i;
          u32x4 q;
          q[0] = pack2(rB[0][i], rB[1][i]);
          q[1] = pack2(rB[2][i], rB[3][i]);
          q[2] = pack2(rB[4][i], rB[5][i]);
          q[3] = pack2(rB[6][i], rB[7][i]);
          *(u32x4*)(Bn + swz(n, kg)) = q;
        }
      }
      cur ^= 1;
    }

    // epilogue: bf16 stores of unweighted y rows
#pragma unroll
    for (int mi2 = 0; mi2 < 4; ++mi2) {
#pragma unroll
      for (int j = 0; j < 4; ++j) {
        int rl = wr*64 + mi2*16 + (lane >> 4)*4 + j;
        if (R0 + rl < count) {
          int sr = base_sorted + rl;
          unsigned short* yrow = y_buf + (size_t)sr * HDIM;
#pragma unroll
          for (int ni = 0; ni < 8; ++ni) {
            int col = nt*256 + wc*128 + ni*16 + (lane & 15);
            yrow[col] = f2bf(acc[mi2][ni][j]);
          }
        }
      }
    }
  }
}

// ---------------- finalize: out[t] = sum_k tw[t,k] * y_buf[sortpos[t,k]] ----------------
__global__ __launch_bounds__(256) void k_finalize(
    const unsigned short* __restrict__ y_buf, const int* __restrict__ sortpos,
    const float* __restrict__ tw, float* __restrict__ out)
{
  const int t = blockIdx.x;
  const int tid = threadIdx.x;   // each thread: 8 consecutive cols
  float acc[8];
#pragma unroll
  for (int i = 0; i < 8; ++i) acc[i] = 0.f;
#pragma unroll
  for (int k = 0; k < 4; ++k) {
    int sp = sortpos[t*4+k];
    float w = tw[t*4+k];
    if (sp >= 0) {
      u32x4 v = *(const u32x4*)(y_buf + (size_t)sp * HDIM + tid*8);
#pragma unroll
      for (int q = 0; q < 4; ++q) {
        float lo = __builtin_bit_cast(float, v[q] << 16);
        float hi = __builtin_bit_cast(float, v[q] & 0xffff0000u);
        acc[2*q]   += w * lo;
        acc[2*q+1] += w * hi;
      }
    }
  }
  f32x4 o0 = {acc[0], acc[1], acc[2], acc[3]};
  f32x4 o1 = {acc[4], acc[5], acc[6], acc[7]};
  f32x4* o = (f32x4*)(out + (size_t)t * HDIM + tid*8);
  o[0] = o0;
  o[1] = o1;
}

extern "C" void kernel_launch(void* const* d_in, const int* in_sizes, int n_in,
                              void* d_out, int out_size, void* d_ws, size_t ws_size,
                              hipStream_t stream) {
  const float* hs  = (const float*)d_in[0];
  const float* gw  = (const float*)d_in[1];
  const float* w13 = (const float*)d_in[2];
  const float* w2  = (const float*)d_in[3];
  float* out = (float*)d_out;

  char* ws = (char*)d_ws;
  size_t off = 0;
  auto alloc = [&](size_t bytes) {
    off = (off + 255) & ~(size_t)255;
    char* p = ws + off;
    off += bytes;
    return p;
  };
  unsigned short* hs_bf = (unsigned short*)alloc((size_t)T_TOK * HDIM * 2);
  int*   tidx   = (int*)  alloc((size_t)NFLAT * 4);
  float* tw     = (float*)alloc((size_t)NFLAT * 4);
  int*   rankb  = (int*)  alloc((size_t)NFLAT * 4);
  int*   counts = (int*)  alloc((size_t)NEXP * 4);
  int*   starts = (int*)  alloc((size_t)NEXP * 4);
  int*   rinfo  = (int*)  alloc((size_t)NFLAT * 4);
  int*   sortp  = (int*)  alloc((size_t)NFLAT * 4);
  unsigned short* a_buf = (unsigned short*)alloc((size_t)NFLAT * IDIM * 2);
  unsigned short* y_buf = (unsigned short*)alloc((size_t)NFLAT * HDIM * 2);
  (void)ws_size; (void)in_sizes; (void)n_in; (void)out_size;

  k_gating<<<T_TOK/16, 256, 0, stream>>>(hs, gw, hs_bf, tidx, tw);
  k_count_rank<<<NEXP, 64, 0, stream>>>(tidx, rankb, counts);
  k_build<<<1, 256, 0, stream>>>(tidx, rankb, counts, starts, rinfo, sortp);
  k_gemm1<<<dim3(6, NEXP), 512, 0, stream>>>(hs_bf, w13, counts, starts, rinfo, a_buf);
  k_gemm2<<<dim3(8, NEXP), 512, 0, stream>>>(a_buf, w2, counts, starts, y_buf);
  k_finalize<<<T_TOK, 256, 0, stream>>>(y_buf, sortp, tw, out);
}